// Round 7
// baseline (166.240 us; speedup 1.0000x reference)
//
#include <hip/hip_runtime.h>
#include <hip/hip_bf16.h>

// DynamicFilter fused, R21 = R20 (persistent tile) with loop-carried register
// set cut ~30 to end spilling under the 128-VGPR cap.
//
// R20 post-mortem: 119 -> 95us from conv2 NTC=1, but VGPR still pinned 128,
// WRITE 28.4MB = 8.2 output + ~20MB spill (FETCH 37.5MB = clean input*2.25
// halo factor). R19->R20 isolates spill cost: ~15MB spill removed = 24us.
// R21 shrinks CARRIED state only; every memory access pattern (LDS reads,
// gathers, MFMA counts, conflicts) identical to R20:
//  1. bfr reloaded per batch-iter via laundered zero offset (asm volatile
//     opaque -> no LICM; w1c L1-hot) -> dead during conv2, -16 carried.
//  2. t0o/t1o packed (t1o<<16|t0o) in 4 regs, unpacked to conv1-locals -> -8.
//  3. t1m recomputed per iter from kg*4+j<=8 (conv1-local) -> -4.
//  4. eo packed 4x8bit in 1 reg (max 125), unpacked post-conv2 -> -3.
// Predict: VGPR 105-118 (unpinned), WRITE exactly 8192KB, FETCH ~33.5MB,
// main 95 -> 80-85us. If spill-free but >=92us: spill theory exhausted ->
// LDS pipe (~74% busy est.) confirmed bottleneck -> restructure gather next.
//
// LDS: xs0f 2.3K + pxc 2.3K + hs 32K = 36.6KB -> 4 blocks/CU.
// d_ws: w1c bf16 [32ch][64k] @0 (k>=50 zero), w2t bf16 [25tap][16f][32chpos]
// @4096 (f>=9 zero; chpos 2i->ch i, 2i+1->ch 16+i).

typedef __attribute__((ext_vector_type(8))) short bf16x8;
typedef __attribute__((ext_vector_type(4))) float f32x4;

#define HH 512
#define WW 512
#define TILE 16
#define XS_H 24
#define XS_W 24
#define XS_N (XS_H * XS_W)     // 576
#define HS_R 20
#define HS_C 20
#define PXS 40                 // shorts per px in hs (80B stride)

__device__ __forceinline__ unsigned short f2bf(float x) {
    union { float f; unsigned int u; } v; v.f = x;
    unsigned int u = v.u;
    u += 0x7FFFu + ((u >> 16) & 1u);   // round-to-nearest-even
    return (unsigned short)(u >> 16);
}

__device__ __forceinline__ unsigned int pack_bf2(float a, float b) {
    __hip_bfloat162 h2 = __float22bfloat162_rn(make_float2(a, b));
    union { __hip_bfloat162 h; unsigned int u; } cv; cv.h = h2;
    return cv.u;
}

__device__ __forceinline__ bf16x8 dw4_to_frag(unsigned int d0, unsigned int d1,
                                              unsigned int d2, unsigned int d3) {
    union { unsigned int u[4]; bf16x8 f; } cv;
    cv.u[0] = d0; cv.u[1] = d1; cv.u[2] = d2; cv.u[3] = d3;
    return cv.f;
}

__global__ void dynfilt_prep(const float* __restrict__ w1,
                             const float* __restrict__ w2,
                             unsigned short* __restrict__ w1c,
                             unsigned short* __restrict__ w2t)
{
    int gid = blockIdx.x * 256 + threadIdx.x;   // 8192 threads
    // w1c[ch32][k64]: k = 2*tap + ci; k>=50 -> 0
    for (int i = gid; i < 32 * 64; i += 8192) {
        int ch = i >> 6, k = i & 63;
        int tap = k >> 1, ci = k & 1;
        w1c[i] = (k < 50) ? f2bf(w1[(ch * 2 + ci) * 25 + tap]) : (unsigned short)0;
    }
    // w2t[tap25][f16][chpos32]: chpos 2i -> ch i, 2i+1 -> ch 16+i; f>=9 zero
    for (int i = gid; i < 25 * 16 * 32; i += 8192) {
        int p = i & 31;
        int f = (i >> 5) & 15;
        int tap = i >> 9;   // 0..24
        int ch = (p & 1) * 16 + (p >> 1);
        w2t[i] = (f < 9) ? f2bf(w2[(f * 32 + ch) * 25 + tap]) : (unsigned short)0;
    }
}

// conv2 pass over single tap-col TC0: rolling 4-row B-frag buffer.
// B-frag(row = wv*4 + i + tr, col = n + TC0) shared across (i,tr) with equal
// i+tr; rows rotate through R[.&3]. All indices compile-time after unroll.
template<int TC0>
__device__ __forceinline__ void conv2_pass(const unsigned short* hsp,
                                           const unsigned short* __restrict__ w2t,
                                           int wv, int n, int kg, f32x4* acc) {
    bf16x8 R[4];
    #pragma unroll
    for (int q = 0; q < 4; ++q)
        R[q] = *(const bf16x8*)(hsp + ((wv * 4 + q) * HS_C + n + TC0) * PXS + kg * 8);
    #pragma unroll
    for (int tr = 0; tr < 5; ++tr) {
        bf16x8 afr = *(const bf16x8*)(w2t + ((tr * 5 + TC0) * 16 + n) * 32 + kg * 8);
        #pragma unroll
        for (int i = 0; i < 4; ++i)
            acc[i] = __builtin_amdgcn_mfma_f32_16x16x32_bf16(afr, R[(tr + i) & 3], acc[i], 0, 0, 0);
        if (tr < 4)
            R[tr & 3] = *(const bf16x8*)(hsp + ((wv * 4 + tr + 4) * HS_C + n + TC0) * PXS + kg * 8);
    }
}

__global__
__attribute__((amdgpu_flat_work_group_size(256, 256), amdgpu_waves_per_eu(2)))
void dynfilt_main(const float* __restrict__ image,
                  const float* __restrict__ refer,
                  const float* __restrict__ b1,
                  const float* __restrict__ b2,
                  const unsigned short* __restrict__ w1c,
                  const unsigned short* __restrict__ w2t,
                  float* __restrict__ out)
{
    __shared__ float xs0f[XS_N];                // image fp32 (epilogue), flat
    __shared__ unsigned int pxc[XS_N];          // packed (bf16 img | bf16 ref)
    __shared__ __align__(16) unsigned short hs[HS_R * HS_C * PXS];

    const int t   = threadIdx.x;
    const int gx0 = blockIdx.x * TILE;
    const int gy0 = blockIdx.y * TILE;

    // whole halo (rows gy0-4..+19, cols gx0-4..+19) in-bounds?
    const bool interior = (gy0 >= 4) && (gy0 + XS_H - 4 <= HH) &&
                          (gx0 >= 4) && (gx0 + XS_W - 4 <= WW);

    // ---- batch-invariant staging offsets (sentinel -1 = skip) ----
    int soff[3];
    #pragma unroll
    for (int k = 0; k < 3; ++k) {
        int idx = t + k * 256;
        int r = idx / XS_W, c = idx - (idx / XS_W) * XS_W;
        int gy = gy0 - 4 + r, gx = gx0 - 4 + c;
        bool inb = (idx < XS_N) & ((unsigned)gy < HH) & ((unsigned)gx < WW);
        soff[k] = inb ? (gy * WW + gx) : -1;
    }

    const int lane = t & 63;
    const int wv   = t >> 6;
    const int n    = lane & 15;
    const int kg   = lane >> 4;

    // ---- per-lane pxc offsets, packed: toff[j] = t0o | (t1o<<16) ----
    unsigned int toff[4];
    #pragma unroll
    for (int j = 0; j < 4; ++j) {
        int tap0 = kg * 4 + j;                       // 0..15, always valid
        int o0 = (tap0 / 5) * XS_W + tap0 % 5;       // <= 76
        int tap1 = 16 + kg * 4 + j;                  // valid iff <= 24
        int tc   = (tap1 <= 24) ? tap1 : 0;
        int o1 = (tc / 5) * XS_W + tc % 5;           // <= 100
        toff[j] = (unsigned)o0 | ((unsigned)o1 << 16);
    }

    // px = mt*16 + n raster start (pr0,pc0) over 20-wide h grid
    int px0 = wv * 16 + n;
    const int pr0 = px0 / 20, pc0 = px0 - (px0 / 20) * 20;

    const float bb0 = b1[n], bb1 = b1[16 + n];

    // ---- conv2 / epilogue constants (once); eo packed 4x8bit ----
    float b2r[4];
    unsigned int eopk = 0;
    #pragma unroll
    for (int r2 = 0; r2 < 4; ++r2) {
        int f = kg * 4 + r2;
        b2r[r2] = (f < 9) ? b2[f] : 0.f;
        int fy = f / 3, fx = f - fy * 3;
        unsigned int e = (fy + 3) * XS_W + fx + 3;   // <= 125
        eopk |= e << (8 * r2);
    }

    // ---- prefetch batch 0 halo into regs ----
    float pvI[3], pvR[3];
    #pragma unroll
    for (int k = 0; k < 3; ++k) {
        pvI[k] = 0.f; pvR[k] = 0.f;
        if (soff[k] >= 0) {
            pvI[k] = image[soff[k]];
            pvR[k] = refer[soff[k]];
        }
    }

    #pragma unroll 1
    for (int bb = 0; bb < 8; ++bb) {
        // ---- stage write from prefetch regs ----
        #pragma unroll
        for (int k = 0; k < 3; ++k) {
            int idx = t + k * 256;
            if (idx < XS_N) {
                xs0f[idx] = pvI[k];
                pxc[idx]  = pack_bf2(pvI[k], pvR[k]);
            }
        }
        __syncthreads();   // A: xs0f/pxc ready

        // ---- issue next batch's prefetch (hides under conv1+conv2) ----
        if (bb < 7) {
            const float* ibn = image + (size_t)(bb + 1) * (HH * WW);
            const float* rbn = refer + (size_t)(bb + 1) * (HH * WW);
            #pragma unroll
            for (int k = 0; k < 3; ++k) {
                pvI[k] = 0.f; pvR[k] = 0.f;
                if (soff[k] >= 0) {
                    pvI[k] = ibn[soff[k]];
                    pvR[k] = rbn[soff[k]];
                }
            }
        }

        // ---- conv1 B-frags: reloaded EVERY iter via laundered offset so the
        //      16 regs are dead during conv2 (w1c is L1-hot; no LICM) ----
        int lzero = 0;
        asm volatile("" : "+v"(lzero));              // opaque zero
        const unsigned short* w1cl = w1c + lzero;
        bf16x8 bfr[2][2];
        #pragma unroll
        for (int nt = 0; nt < 2; ++nt)
            #pragma unroll
            for (int s = 0; s < 2; ++s)
                bfr[nt][s] = *(const bf16x8*)(w1cl + (nt * 16 + n) * 64 + s * 32 + kg * 8);

        // ---- unpack gather offsets + masks (conv1-local) ----
        int t0o[4], t1o[4];
        unsigned int t1m[4];
        #pragma unroll
        for (int j = 0; j < 4; ++j) {
            t0o[j] = (int)(toff[j] & 0xFFFFu);
            t1o[j] = (int)(toff[j] >> 16);
            t1m[j] = (kg * 4 + j <= 8) ? 0xFFFFFFFFu : 0u;
        }

        // ---- conv1 GEMM + fused leaky+pack write to hs ----
        int pr = pr0, pc = pc0;
        if (interior) {
            unsigned short* hp0 = hs + (wv * 16 + kg * 4) * PXS + 2 * n;
            #pragma unroll
            for (int m = 0; m < 7; ++m) {
                int mt = m * 4 + wv;
                if (mt < 25) {   // wave-uniform guard
                    const unsigned int* base = pxc + (pr * XS_W + pc);
                    unsigned int a0d[4], a1d[4];
                    #pragma unroll
                    for (int j = 0; j < 4; ++j) a0d[j] = base[t0o[j]];
                    #pragma unroll
                    for (int j = 0; j < 4; ++j) a1d[j] = base[t1o[j]] & t1m[j];
                    bf16x8 a0 = dw4_to_frag(a0d[0], a0d[1], a0d[2], a0d[3]);
                    bf16x8 a1 = dw4_to_frag(a1d[0], a1d[1], a1d[2], a1d[3]);
                    f32x4 d0 = (f32x4){bb0, bb0, bb0, bb0};
                    f32x4 d1 = (f32x4){bb1, bb1, bb1, bb1};
                    d0 = __builtin_amdgcn_mfma_f32_16x16x32_bf16(a0, bfr[0][0], d0, 0, 0, 0);
                    d0 = __builtin_amdgcn_mfma_f32_16x16x32_bf16(a1, bfr[0][1], d0, 0, 0, 0);
                    d1 = __builtin_amdgcn_mfma_f32_16x16x32_bf16(a0, bfr[1][0], d1, 0, 0, 0);
                    d1 = __builtin_amdgcn_mfma_f32_16x16x32_bf16(a1, bfr[1][1], d1, 0, 0, 0);
                    #pragma unroll
                    for (int r = 0; r < 4; ++r) {
                        float h0 = fmaxf(d0[r], 0.1f * d0[r]);
                        float h1 = fmaxf(d1[r], 0.1f * d1[r]);
                        *(unsigned int*)(hp0 + (m * 64 + r) * PXS) = pack_bf2(h0, h1);
                    }
                }
                pc += 4; pr += 3;
                int w = (pc >= 20) ? 1 : 0;
                pc -= 20 * w; pr += w;
            }
        } else {
            #pragma unroll
            for (int m = 0; m < 7; ++m) {
                int mt = m * 4 + wv;
                if (mt < 25) {
                    const unsigned int* base = pxc + (pr * XS_W + pc);
                    unsigned int a0d[4], a1d[4];
                    #pragma unroll
                    for (int j = 0; j < 4; ++j) a0d[j] = base[t0o[j]];
                    #pragma unroll
                    for (int j = 0; j < 4; ++j) a1d[j] = base[t1o[j]] & t1m[j];
                    bf16x8 a0 = dw4_to_frag(a0d[0], a0d[1], a0d[2], a0d[3]);
                    bf16x8 a1 = dw4_to_frag(a1d[0], a1d[1], a1d[2], a1d[3]);
                    f32x4 d0 = (f32x4){bb0, bb0, bb0, bb0};
                    f32x4 d1 = (f32x4){bb1, bb1, bb1, bb1};
                    d0 = __builtin_amdgcn_mfma_f32_16x16x32_bf16(a0, bfr[0][0], d0, 0, 0, 0);
                    d0 = __builtin_amdgcn_mfma_f32_16x16x32_bf16(a1, bfr[0][1], d0, 0, 0, 0);
                    d1 = __builtin_amdgcn_mfma_f32_16x16x32_bf16(a0, bfr[1][0], d1, 0, 0, 0);
                    d1 = __builtin_amdgcn_mfma_f32_16x16x32_bf16(a1, bfr[1][1], d1, 0, 0, 0);
                    #pragma unroll
                    for (int r = 0; r < 4; ++r) {
                        int px = mt * 16 + kg * 4 + r;   // D row = (lane>>4)*4 + reg
                        int prr = px / HS_C, pcc = px - prr * HS_C;
                        int gy = gy0 - 2 + prr, gx = gx0 - 2 + pcc;
                        bool inb = ((unsigned)gy < HH) & ((unsigned)gx < WW);
                        float h0 = fmaxf(d0[r], 0.1f * d0[r]);
                        float h1 = fmaxf(d1[r], 0.1f * d1[r]);
                        if (!inb) { h0 = 0.f; h1 = 0.f; }
                        *(unsigned int*)(hs + px * PXS + 2 * n) = pack_bf2(h0, h1);
                    }
                }
                pc += 4; pr += 3;
                int w = (pc >= 20) ? 1 : 0;
                pc -= 20 * w; pr += w;
            }
        }
        __syncthreads();   // B: hs ready

        // ---- conv2: rolling-row MFMA GEMM (5 single-col passes), b2-init ----
        f32x4 acc[4];
        #pragma unroll
        for (int i = 0; i < 4; ++i)
            acc[i] = (f32x4){b2r[0], b2r[1], b2r[2], b2r[3]};

        conv2_pass<0>(hs, w2t, wv, n, kg, acc);
        conv2_pass<1>(hs, w2t, wv, n, kg, acc);
        conv2_pass<2>(hs, w2t, wv, n, kg, acc);
        conv2_pass<3>(hs, w2t, wv, n, kg, acc);
        conv2_pass<4>(hs, w2t, wv, n, kg, acc);

        // ---- epilogue: out = sum_f filt_f * image[y+fy-1][x+fx-1] ----
        int eo[4];
        #pragma unroll
        for (int r2 = 0; r2 < 4; ++r2)
            eo[r2] = (int)((eopk >> (8 * r2)) & 0xFFu);
        #pragma unroll
        for (int i = 0; i < 4; ++i) {
            int py = wv * 4 + i;
            float partial = 0.f;
            #pragma unroll
            for (int r2 = 0; r2 < 4; ++r2)
                partial += acc[i][r2] * xs0f[py * XS_W + n + eo[r2]];   // f>=9 term exact-zero
            partial += __shfl_down(partial, 16, 64);
            partial += __shfl_down(partial, 32, 64);
            if (lane < 16)
                out[((size_t)bb * HH + gy0 + py) * WW + gx0 + n] = partial;
        }
        __syncthreads();   // C: xs0f/pxc/hs free for next batch
    }
}

extern "C" void kernel_launch(void* const* d_in, const int* in_sizes, int n_in,
                              void* d_out, int out_size, void* d_ws, size_t ws_size,
                              hipStream_t stream) {
    const float* image = (const float*)d_in[0];
    const float* refer = (const float*)d_in[1];
    const float* w1    = (const float*)d_in[2];
    const float* b1    = (const float*)d_in[3];
    const float* w2    = (const float*)d_in[4];
    const float* b2    = (const float*)d_in[5];

    unsigned short* w1c = (unsigned short*)d_ws;                   // 4 KB
    unsigned short* w2t = (unsigned short*)((char*)d_ws + 4096);   // 25.6 KB
    // ws re-poisoned before every launch -> prep must (and does) run every call

    hipLaunchKernelGGL(dynfilt_prep, dim3(32), dim3(256), 0, stream, w1, w2, w1c, w2t);

    dim3 grid(WW / TILE, HH / TILE, 1);   // persistent over batch: 1024 blocks
    hipLaunchKernelGGL(dynfilt_main, grid, dim3(256), 0, stream,
                       image, refer, b1, b2, w1c, w2t, (float*)d_out);
}

// Round 8
// 153.613 us; speedup vs baseline: 1.0822x; 1.0822x over previous
//
#include <hip/hip_runtime.h>
#include <hip/hip_bf16.h>

// DynamicFilter fused, R23 = R20 structure + R21's carried-reg cuts, WITHOUT
// R21's bfr-per-iter reload (that was the regression).
//
// R21 post-mortem: spills gone (WRITE 8192KB exact, VGPR 124) but 95->122us.
// All util counters scaled by ~1.28x -> same work, more stall. Regression
// isolates to bfr reload: 4 dependent global loads + asm pin at head of
// every conv1 phase x8 iters, only 16 waves/CU to hide it. The packing cuts
// (toff 4 regs, t1m recomputed, eopk 1 reg; -15 carried) are what freed the
// allocator. R20-with-spill (95) < R21-no-spill (122): effects confounded.
// R23 separates: bfr loaded ONCE pre-loop (R20), packing cuts kept (R21).
// Carried ~44 + conv2 peak ~84 -> under 128 without tricks.
// Predict: VGPR 110-124 unpinned, WRITE exactly 8192KB, FETCH ~32.5MB.
// If R20's residual ~20MB spill was real cost: main 95 -> 82-88us. If ~95
// with clean counters: spills were free, R19->R20 win was conv2 NTC change,
// next target = LDS pipe (~72% busy est): conv1 gather b128 via K-perm.
//
// LDS: xs0f 2.3K + pxc 2.3K + hs 32K = 36.6KB -> 4 blocks/CU.
// d_ws: w1c bf16 [32ch][64k] @0 (k>=50 zero), w2t bf16 [25tap][16f][32chpos]
// @4096 (f>=9 zero; chpos 2i->ch i, 2i+1->ch 16+i).

typedef __attribute__((ext_vector_type(8))) short bf16x8;
typedef __attribute__((ext_vector_type(4))) float f32x4;

#define HH 512
#define WW 512
#define TILE 16
#define XS_H 24
#define XS_W 24
#define XS_N (XS_H * XS_W)     // 576
#define HS_R 20
#define HS_C 20
#define PXS 40                 // shorts per px in hs (80B stride)

__device__ __forceinline__ unsigned short f2bf(float x) {
    union { float f; unsigned int u; } v; v.f = x;
    unsigned int u = v.u;
    u += 0x7FFFu + ((u >> 16) & 1u);   // round-to-nearest-even
    return (unsigned short)(u >> 16);
}

__device__ __forceinline__ unsigned int pack_bf2(float a, float b) {
    __hip_bfloat162 h2 = __float22bfloat162_rn(make_float2(a, b));
    union { __hip_bfloat162 h; unsigned int u; } cv; cv.h = h2;
    return cv.u;
}

__device__ __forceinline__ bf16x8 dw4_to_frag(unsigned int d0, unsigned int d1,
                                              unsigned int d2, unsigned int d3) {
    union { unsigned int u[4]; bf16x8 f; } cv;
    cv.u[0] = d0; cv.u[1] = d1; cv.u[2] = d2; cv.u[3] = d3;
    return cv.f;
}

__global__ void dynfilt_prep(const float* __restrict__ w1,
                             const float* __restrict__ w2,
                             unsigned short* __restrict__ w1c,
                             unsigned short* __restrict__ w2t)
{
    int gid = blockIdx.x * 256 + threadIdx.x;   // 8192 threads
    // w1c[ch32][k64]: k = 2*tap + ci; k>=50 -> 0
    for (int i = gid; i < 32 * 64; i += 8192) {
        int ch = i >> 6, k = i & 63;
        int tap = k >> 1, ci = k & 1;
        w1c[i] = (k < 50) ? f2bf(w1[(ch * 2 + ci) * 25 + tap]) : (unsigned short)0;
    }
    // w2t[tap25][f16][chpos32]: chpos 2i -> ch i, 2i+1 -> ch 16+i; f>=9 zero
    for (int i = gid; i < 25 * 16 * 32; i += 8192) {
        int p = i & 31;
        int f = (i >> 5) & 15;
        int tap = i >> 9;   // 0..24
        int ch = (p & 1) * 16 + (p >> 1);
        w2t[i] = (f < 9) ? f2bf(w2[(f * 32 + ch) * 25 + tap]) : (unsigned short)0;
    }
}

// conv2 pass over single tap-col TC0: rolling 4-row B-frag buffer.
// B-frag(row = wv*4 + i + tr, col = n + TC0) shared across (i,tr) with equal
// i+tr; rows rotate through R[.&3]. All indices compile-time after unroll.
template<int TC0>
__device__ __forceinline__ void conv2_pass(const unsigned short* hsp,
                                           const unsigned short* __restrict__ w2t,
                                           int wv, int n, int kg, f32x4* acc) {
    bf16x8 R[4];
    #pragma unroll
    for (int q = 0; q < 4; ++q)
        R[q] = *(const bf16x8*)(hsp + ((wv * 4 + q) * HS_C + n + TC0) * PXS + kg * 8);
    #pragma unroll
    for (int tr = 0; tr < 5; ++tr) {
        bf16x8 afr = *(const bf16x8*)(w2t + ((tr * 5 + TC0) * 16 + n) * 32 + kg * 8);
        #pragma unroll
        for (int i = 0; i < 4; ++i)
            acc[i] = __builtin_amdgcn_mfma_f32_16x16x32_bf16(afr, R[(tr + i) & 3], acc[i], 0, 0, 0);
        if (tr < 4)
            R[tr & 3] = *(const bf16x8*)(hsp + ((wv * 4 + tr + 4) * HS_C + n + TC0) * PXS + kg * 8);
    }
}

__global__
__attribute__((amdgpu_flat_work_group_size(256, 256), amdgpu_waves_per_eu(2)))
void dynfilt_main(const float* __restrict__ image,
                  const float* __restrict__ refer,
                  const float* __restrict__ b1,
                  const float* __restrict__ b2,
                  const unsigned short* __restrict__ w1c,
                  const unsigned short* __restrict__ w2t,
                  float* __restrict__ out)
{
    __shared__ float xs0f[XS_N];                // image fp32 (epilogue), flat
    __shared__ unsigned int pxc[XS_N];          // packed (bf16 img | bf16 ref)
    __shared__ __align__(16) unsigned short hs[HS_R * HS_C * PXS];

    const int t   = threadIdx.x;
    const int gx0 = blockIdx.x * TILE;
    const int gy0 = blockIdx.y * TILE;

    // whole halo (rows gy0-4..+19, cols gx0-4..+19) in-bounds?
    const bool interior = (gy0 >= 4) && (gy0 + XS_H - 4 <= HH) &&
                          (gx0 >= 4) && (gx0 + XS_W - 4 <= WW);

    // ---- batch-invariant staging offsets (sentinel -1 = skip) ----
    int soff[3];
    #pragma unroll
    for (int k = 0; k < 3; ++k) {
        int idx = t + k * 256;
        int r = idx / XS_W, c = idx - (idx / XS_W) * XS_W;
        int gy = gy0 - 4 + r, gx = gx0 - 4 + c;
        bool inb = (idx < XS_N) & ((unsigned)gy < HH) & ((unsigned)gx < WW);
        soff[k] = inb ? (gy * WW + gx) : -1;
    }

    const int lane = t & 63;
    const int wv   = t >> 6;
    const int n    = lane & 15;
    const int kg   = lane >> 4;

    // ---- conv1 B-frags: loaded ONCE, carried (w1c L1-hot) ----
    bf16x8 bfr[2][2];
    #pragma unroll
    for (int nt = 0; nt < 2; ++nt)
        #pragma unroll
        for (int s = 0; s < 2; ++s)
            bfr[nt][s] = *(const bf16x8*)(w1c + (nt * 16 + n) * 64 + s * 32 + kg * 8);

    // ---- per-lane pxc offsets, packed: toff[j] = t0o | (t1o<<16) ----
    unsigned int toff[4];
    #pragma unroll
    for (int j = 0; j < 4; ++j) {
        int tap0 = kg * 4 + j;                       // 0..15, always valid
        int o0 = (tap0 / 5) * XS_W + tap0 % 5;       // <= 76
        int tap1 = 16 + kg * 4 + j;                  // valid iff <= 24
        int tc   = (tap1 <= 24) ? tap1 : 0;
        int o1 = (tc / 5) * XS_W + tc % 5;           // <= 100
        toff[j] = (unsigned)o0 | ((unsigned)o1 << 16);
    }

    // px = mt*16 + n raster start (pr0,pc0) over 20-wide h grid
    int px0 = wv * 16 + n;
    const int pr0 = px0 / 20, pc0 = px0 - (px0 / 20) * 20;

    const float bb0 = b1[n], bb1 = b1[16 + n];

    // ---- conv2 / epilogue constants (once); eo packed 4x8bit ----
    float b2r[4];
    unsigned int eopk = 0;
    #pragma unroll
    for (int r2 = 0; r2 < 4; ++r2) {
        int f = kg * 4 + r2;
        b2r[r2] = (f < 9) ? b2[f] : 0.f;
        int fy = f / 3, fx = f - fy * 3;
        unsigned int e = (fy + 3) * XS_W + fx + 3;   // <= 125
        eopk |= e << (8 * r2);
    }

    // ---- prefetch batch 0 halo into regs ----
    float pvI[3], pvR[3];
    #pragma unroll
    for (int k = 0; k < 3; ++k) {
        pvI[k] = 0.f; pvR[k] = 0.f;
        if (soff[k] >= 0) {
            pvI[k] = image[soff[k]];
            pvR[k] = refer[soff[k]];
        }
    }

    #pragma unroll 1
    for (int bb = 0; bb < 8; ++bb) {
        // ---- stage write from prefetch regs ----
        #pragma unroll
        for (int k = 0; k < 3; ++k) {
            int idx = t + k * 256;
            if (idx < XS_N) {
                xs0f[idx] = pvI[k];
                pxc[idx]  = pack_bf2(pvI[k], pvR[k]);
            }
        }
        __syncthreads();   // A: xs0f/pxc ready

        // ---- issue next batch's prefetch (hides under conv1+conv2) ----
        if (bb < 7) {
            const float* ibn = image + (size_t)(bb + 1) * (HH * WW);
            const float* rbn = refer + (size_t)(bb + 1) * (HH * WW);
            #pragma unroll
            for (int k = 0; k < 3; ++k) {
                pvI[k] = 0.f; pvR[k] = 0.f;
                if (soff[k] >= 0) {
                    pvI[k] = ibn[soff[k]];
                    pvR[k] = rbn[soff[k]];
                }
            }
        }

        // ---- unpack gather offsets + masks (conv1-local regs) ----
        int t0o[4], t1o[4];
        unsigned int t1m[4];
        #pragma unroll
        for (int j = 0; j < 4; ++j) {
            t0o[j] = (int)(toff[j] & 0xFFFFu);
            t1o[j] = (int)(toff[j] >> 16);
            t1m[j] = (kg * 4 + j <= 8) ? 0xFFFFFFFFu : 0u;
        }

        // ---- conv1 GEMM + fused leaky+pack write to hs ----
        int pr = pr0, pc = pc0;
        if (interior) {
            unsigned short* hp0 = hs + (wv * 16 + kg * 4) * PXS + 2 * n;
            #pragma unroll
            for (int m = 0; m < 7; ++m) {
                int mt = m * 4 + wv;
                if (mt < 25) {   // wave-uniform guard
                    const unsigned int* base = pxc + (pr * XS_W + pc);
                    unsigned int a0d[4], a1d[4];
                    #pragma unroll
                    for (int j = 0; j < 4; ++j) a0d[j] = base[t0o[j]];
                    #pragma unroll
                    for (int j = 0; j < 4; ++j) a1d[j] = base[t1o[j]] & t1m[j];
                    bf16x8 a0 = dw4_to_frag(a0d[0], a0d[1], a0d[2], a0d[3]);
                    bf16x8 a1 = dw4_to_frag(a1d[0], a1d[1], a1d[2], a1d[3]);
                    f32x4 d0 = (f32x4){bb0, bb0, bb0, bb0};
                    f32x4 d1 = (f32x4){bb1, bb1, bb1, bb1};
                    d0 = __builtin_amdgcn_mfma_f32_16x16x32_bf16(a0, bfr[0][0], d0, 0, 0, 0);
                    d0 = __builtin_amdgcn_mfma_f32_16x16x32_bf16(a1, bfr[0][1], d0, 0, 0, 0);
                    d1 = __builtin_amdgcn_mfma_f32_16x16x32_bf16(a0, bfr[1][0], d1, 0, 0, 0);
                    d1 = __builtin_amdgcn_mfma_f32_16x16x32_bf16(a1, bfr[1][1], d1, 0, 0, 0);
                    #pragma unroll
                    for (int r = 0; r < 4; ++r) {
                        float h0 = fmaxf(d0[r], 0.1f * d0[r]);
                        float h1 = fmaxf(d1[r], 0.1f * d1[r]);
                        *(unsigned int*)(hp0 + (m * 64 + r) * PXS) = pack_bf2(h0, h1);
                    }
                }
                pc += 4; pr += 3;
                int w = (pc >= 20) ? 1 : 0;
                pc -= 20 * w; pr += w;
            }
        } else {
            #pragma unroll
            for (int m = 0; m < 7; ++m) {
                int mt = m * 4 + wv;
                if (mt < 25) {
                    const unsigned int* base = pxc + (pr * XS_W + pc);
                    unsigned int a0d[4], a1d[4];
                    #pragma unroll
                    for (int j = 0; j < 4; ++j) a0d[j] = base[t0o[j]];
                    #pragma unroll
                    for (int j = 0; j < 4; ++j) a1d[j] = base[t1o[j]] & t1m[j];
                    bf16x8 a0 = dw4_to_frag(a0d[0], a0d[1], a0d[2], a0d[3]);
                    bf16x8 a1 = dw4_to_frag(a1d[0], a1d[1], a1d[2], a1d[3]);
                    f32x4 d0 = (f32x4){bb0, bb0, bb0, bb0};
                    f32x4 d1 = (f32x4){bb1, bb1, bb1, bb1};
                    d0 = __builtin_amdgcn_mfma_f32_16x16x32_bf16(a0, bfr[0][0], d0, 0, 0, 0);
                    d0 = __builtin_amdgcn_mfma_f32_16x16x32_bf16(a1, bfr[0][1], d0, 0, 0, 0);
                    d1 = __builtin_amdgcn_mfma_f32_16x16x32_bf16(a0, bfr[1][0], d1, 0, 0, 0);
                    d1 = __builtin_amdgcn_mfma_f32_16x16x32_bf16(a1, bfr[1][1], d1, 0, 0, 0);
                    #pragma unroll
                    for (int r = 0; r < 4; ++r) {
                        int px = mt * 16 + kg * 4 + r;   // D row = (lane>>4)*4 + reg
                        int prr = px / HS_C, pcc = px - prr * HS_C;
                        int gy = gy0 - 2 + prr, gx = gx0 - 2 + pcc;
                        bool inb = ((unsigned)gy < HH) & ((unsigned)gx < WW);
                        float h0 = fmaxf(d0[r], 0.1f * d0[r]);
                        float h1 = fmaxf(d1[r], 0.1f * d1[r]);
                        if (!inb) { h0 = 0.f; h1 = 0.f; }
                        *(unsigned int*)(hs + px * PXS + 2 * n) = pack_bf2(h0, h1);
                    }
                }
                pc += 4; pr += 3;
                int w = (pc >= 20) ? 1 : 0;
                pc -= 20 * w; pr += w;
            }
        }
        __syncthreads();   // B: hs ready

        // ---- conv2: rolling-row MFMA GEMM (5 single-col passes), b2-init ----
        f32x4 acc[4];
        #pragma unroll
        for (int i = 0; i < 4; ++i)
            acc[i] = (f32x4){b2r[0], b2r[1], b2r[2], b2r[3]};

        conv2_pass<0>(hs, w2t, wv, n, kg, acc);
        conv2_pass<1>(hs, w2t, wv, n, kg, acc);
        conv2_pass<2>(hs, w2t, wv, n, kg, acc);
        conv2_pass<3>(hs, w2t, wv, n, kg, acc);
        conv2_pass<4>(hs, w2t, wv, n, kg, acc);

        // ---- epilogue: out = sum_f filt_f * image[y+fy-1][x+fx-1] ----
        int eo[4];
        #pragma unroll
        for (int r2 = 0; r2 < 4; ++r2)
            eo[r2] = (int)((eopk >> (8 * r2)) & 0xFFu);
        #pragma unroll
        for (int i = 0; i < 4; ++i) {
            int py = wv * 4 + i;
            float partial = 0.f;
            #pragma unroll
            for (int r2 = 0; r2 < 4; ++r2)
                partial += acc[i][r2] * xs0f[py * XS_W + n + eo[r2]];   // f>=9 term exact-zero
            partial += __shfl_down(partial, 16, 64);
            partial += __shfl_down(partial, 32, 64);
            if (lane < 16)
                out[((size_t)bb * HH + gy0 + py) * WW + gx0 + n] = partial;
        }
        __syncthreads();   // C: xs0f/pxc/hs free for next batch
    }
}

extern "C" void kernel_launch(void* const* d_in, const int* in_sizes, int n_in,
                              void* d_out, int out_size, void* d_ws, size_t ws_size,
                              hipStream_t stream) {
    const float* image = (const float*)d_in[0];
    const float* refer = (const float*)d_in[1];
    const float* w1    = (const float*)d_in[2];
    const float* b1    = (const float*)d_in[3];
    const float* w2    = (const float*)d_in[4];
    const float* b2    = (const float*)d_in[5];

    unsigned short* w1c = (unsigned short*)d_ws;                   // 4 KB
    unsigned short* w2t = (unsigned short*)((char*)d_ws + 4096);   // 25.6 KB
    // ws re-poisoned before every launch -> prep must (and does) run every call

    hipLaunchKernelGGL(dynfilt_prep, dim3(32), dim3(256), 0, stream, w1, w2, w1c, w2t);

    dim3 grid(WW / TILE, HH / TILE, 1);   // persistent over batch: 1024 blocks
    hipLaunchKernelGGL(dynfilt_main, grid, dim3(256), 0, stream,
                       image, refer, b1, b2, w1c, w2t, (float*)d_out);
}

// Round 10
// 143.636 us; speedup vs baseline: 1.1574x; 1.0695x over previous
//
#include <hip/hip_runtime.h>
#include <hip/hip_bf16.h>

// DynamicFilter fused, R24 = R23 + conv1 k-permutation for bank-spread gather.
// (Resubmitted unchanged: Round-9 bench was a GPU-acquisition timeout, never ran.)
//
// R23 post-mortem: packing cuts neutral (VGPR re-pinned 128, ~20MB spill,
// 95.6us = R20). Spill thread parked after 2 failed attacks. LDS budget at
// 95.6us: conv2 1920 + gather 1160 + hs 650 + epi 370 + stage 140 +
// CONFLICTS 1043 = 5.3K cyc/tile x32 = 168K cyc/CU = 73% busy -> critical
// pipe. Bank math: conv2 b128 uniform (free), hs/epi 2-way (free); gather's
// 4 kg-groups at tap offsets {0,4,27,18} mod 32 -> 3-4-way overlaps = the
// conflict source.
// R24: permute k (exact: dot over k, w1c built with same perm) so kg-group
// owns image ROW kg: a0 offsets kg*24+j, kg*24%32={0,24,16,8} 8-spaced ->
// <=2 lanes/bank. a1 = row4/col4/corner, also spread. a0 dwords consecutive
// (ds_read2 fusable). t1m masks DELETED (invalid k-slots have zero w1c
// weights; finite garbage x 0 = 0). No other change.
// Predict: conflicts 8.54e6 -> ~2e6, main 95.6 -> 86-90us, MfmaUtil ~31,
// FETCH/WRITE/VGPR unchanged. If conflicts drop but time flat: conflicts
// weren't critical -> attack conv2 read stream or retry occupancy.
//
// LDS: xs0f 2.3K + pxc 2.3K + hs 32K = 36.6KB -> 4 blocks/CU.
// d_ws: w1c bf16 [32ch][64k] @0 (k-perm layout), w2t bf16 [25tap][16f]
// [32chpos] @4096 (f>=9 zero; chpos 2i->ch i, 2i+1->ch 16+i).
// k-perm: k = s*32+kg*8+2*j+ci ; s0: tap=(kg,j); s1,kg0: tap=(4,j);
// s1,kg1: tap=(j,4); s1,kg2,j0: tap=(4,4); else invalid (w1c=0).

typedef __attribute__((ext_vector_type(8))) short bf16x8;
typedef __attribute__((ext_vector_type(4))) float f32x4;

#define HH 512
#define WW 512
#define TILE 16
#define XS_H 24
#define XS_W 24
#define XS_N (XS_H * XS_W)     // 576
#define HS_R 20
#define HS_C 20
#define PXS 40                 // shorts per px in hs (80B stride)

__device__ __forceinline__ unsigned short f2bf(float x) {
    union { float f; unsigned int u; } v; v.f = x;
    unsigned int u = v.u;
    u += 0x7FFFu + ((u >> 16) & 1u);   // round-to-nearest-even
    return (unsigned short)(u >> 16);
}

__device__ __forceinline__ unsigned int pack_bf2(float a, float b) {
    __hip_bfloat162 h2 = __float22bfloat162_rn(make_float2(a, b));
    union { __hip_bfloat162 h; unsigned int u; } cv; cv.h = h2;
    return cv.u;
}

__device__ __forceinline__ bf16x8 dw4_to_frag(unsigned int d0, unsigned int d1,
                                              unsigned int d2, unsigned int d3) {
    union { unsigned int u[4]; bf16x8 f; } cv;
    cv.u[0] = d0; cv.u[1] = d1; cv.u[2] = d2; cv.u[3] = d3;
    return cv.f;
}

__global__ void dynfilt_prep(const float* __restrict__ w1,
                             const float* __restrict__ w2,
                             unsigned short* __restrict__ w1c,
                             unsigned short* __restrict__ w2t)
{
    int gid = blockIdx.x * 256 + threadIdx.x;   // 8192 threads
    // w1c[ch32][k64] with k-perm (see header); invalid slots -> 0
    for (int i = gid; i < 32 * 64; i += 8192) {
        int ch = i >> 6, k = i & 63;
        int s = (k >> 5) & 1, kg = (k >> 3) & 3, j = (k >> 1) & 3, ci = k & 1;
        int tap = 0; bool val = true;
        if (!s)            tap = kg * 5 + j;        // rows 0-3, cols 0-3
        else if (kg == 0)  tap = 20 + j;            // row 4, cols 0-3
        else if (kg == 1)  tap = j * 5 + 4;         // col 4, rows 0-3
        else if (kg == 2) { tap = 24; val = (j == 0); }   // corner (4,4)
        else               val = false;
        w1c[i] = val ? f2bf(w1[(ch * 2 + ci) * 25 + tap]) : (unsigned short)0;
    }
    // w2t[tap25][f16][chpos32]: chpos 2i -> ch i, 2i+1 -> ch 16+i; f>=9 zero
    for (int i = gid; i < 25 * 16 * 32; i += 8192) {
        int p = i & 31;
        int f = (i >> 5) & 15;
        int tap = i >> 9;   // 0..24
        int ch = (p & 1) * 16 + (p >> 1);
        w2t[i] = (f < 9) ? f2bf(w2[(f * 32 + ch) * 25 + tap]) : (unsigned short)0;
    }
}

// conv2 pass over single tap-col TC0: rolling 4-row B-frag buffer.
// B-frag(row = wv*4 + i + tr, col = n + TC0) shared across (i,tr) with equal
// i+tr; rows rotate through R[.&3]. All indices compile-time after unroll.
template<int TC0>
__device__ __forceinline__ void conv2_pass(const unsigned short* hsp,
                                           const unsigned short* __restrict__ w2t,
                                           int wv, int n, int kg, f32x4* acc) {
    bf16x8 R[4];
    #pragma unroll
    for (int q = 0; q < 4; ++q)
        R[q] = *(const bf16x8*)(hsp + ((wv * 4 + q) * HS_C + n + TC0) * PXS + kg * 8);
    #pragma unroll
    for (int tr = 0; tr < 5; ++tr) {
        bf16x8 afr = *(const bf16x8*)(w2t + ((tr * 5 + TC0) * 16 + n) * 32 + kg * 8);
        #pragma unroll
        for (int i = 0; i < 4; ++i)
            acc[i] = __builtin_amdgcn_mfma_f32_16x16x32_bf16(afr, R[(tr + i) & 3], acc[i], 0, 0, 0);
        if (tr < 4)
            R[tr & 3] = *(const bf16x8*)(hsp + ((wv * 4 + tr + 4) * HS_C + n + TC0) * PXS + kg * 8);
    }
}

__global__
__attribute__((amdgpu_flat_work_group_size(256, 256), amdgpu_waves_per_eu(2)))
void dynfilt_main(const float* __restrict__ image,
                  const float* __restrict__ refer,
                  const float* __restrict__ b1,
                  const float* __restrict__ b2,
                  const unsigned short* __restrict__ w1c,
                  const unsigned short* __restrict__ w2t,
                  float* __restrict__ out)
{
    __shared__ float xs0f[XS_N];                // image fp32 (epilogue), flat
    __shared__ unsigned int pxc[XS_N];          // packed (bf16 img | bf16 ref)
    __shared__ __align__(16) unsigned short hs[HS_R * HS_C * PXS];

    const int t   = threadIdx.x;
    const int gx0 = blockIdx.x * TILE;
    const int gy0 = blockIdx.y * TILE;

    // whole halo (rows gy0-4..+19, cols gx0-4..+19) in-bounds?
    const bool interior = (gy0 >= 4) && (gy0 + XS_H - 4 <= HH) &&
                          (gx0 >= 4) && (gx0 + XS_W - 4 <= WW);

    // ---- batch-invariant staging offsets (sentinel -1 = skip) ----
    int soff[3];
    #pragma unroll
    for (int k = 0; k < 3; ++k) {
        int idx = t + k * 256;
        int r = idx / XS_W, c = idx - (idx / XS_W) * XS_W;
        int gy = gy0 - 4 + r, gx = gx0 - 4 + c;
        bool inb = (idx < XS_N) & ((unsigned)gy < HH) & ((unsigned)gx < WW);
        soff[k] = inb ? (gy * WW + gx) : -1;
    }

    const int lane = t & 63;
    const int wv   = t >> 6;
    const int n    = lane & 15;
    const int kg   = lane >> 4;

    // ---- conv1 B-frags: loaded ONCE, carried (w1c L1-hot) ----
    bf16x8 bfr[2][2];
    #pragma unroll
    for (int nt = 0; nt < 2; ++nt)
        #pragma unroll
        for (int s = 0; s < 2; ++s)
            bfr[nt][s] = *(const bf16x8*)(w1c + (nt * 16 + n) * 64 + s * 32 + kg * 8);

    // ---- a1 gather offsets (k-perm layout), packed 4x8bit; invalid -> 0
    //      (broadcast read, zero weight in w1c makes the product exact-0) ----
    unsigned int a1opk = 0;
    #pragma unroll
    for (int j = 0; j < 4; ++j) {
        int o = (kg == 0) ? (4 * XS_W + j)                  // row 4, col j
              : (kg == 1) ? (j * XS_W + 4)                  // row j, col 4
              : (kg == 2 && j == 0) ? (4 * XS_W + 4) : 0;   // corner / dummy
        a1opk |= (unsigned)o << (8 * j);
    }

    // px = mt*16 + n raster start (pr0,pc0) over 20-wide h grid
    int px0 = wv * 16 + n;
    const int pr0 = px0 / 20, pc0 = px0 - (px0 / 20) * 20;

    const float bb0 = b1[n], bb1 = b1[16 + n];

    // ---- conv2 / epilogue constants (once); eo packed 4x8bit ----
    float b2r[4];
    unsigned int eopk = 0;
    #pragma unroll
    for (int r2 = 0; r2 < 4; ++r2) {
        int f = kg * 4 + r2;
        b2r[r2] = (f < 9) ? b2[f] : 0.f;
        int fy = f / 3, fx = f - fy * 3;
        unsigned int e = (fy + 3) * XS_W + fx + 3;   // <= 125
        eopk |= e << (8 * r2);
    }

    // ---- prefetch batch 0 halo into regs ----
    float pvI[3], pvR[3];
    #pragma unroll
    for (int k = 0; k < 3; ++k) {
        pvI[k] = 0.f; pvR[k] = 0.f;
        if (soff[k] >= 0) {
            pvI[k] = image[soff[k]];
            pvR[k] = refer[soff[k]];
        }
    }

    #pragma unroll 1
    for (int bb = 0; bb < 8; ++bb) {
        // ---- stage write from prefetch regs ----
        #pragma unroll
        for (int k = 0; k < 3; ++k) {
            int idx = t + k * 256;
            if (idx < XS_N) {
                xs0f[idx] = pvI[k];
                pxc[idx]  = pack_bf2(pvI[k], pvR[k]);
            }
        }
        __syncthreads();   // A: xs0f/pxc ready

        // ---- issue next batch's prefetch (hides under conv1+conv2) ----
        if (bb < 7) {
            const float* ibn = image + (size_t)(bb + 1) * (HH * WW);
            const float* rbn = refer + (size_t)(bb + 1) * (HH * WW);
            #pragma unroll
            for (int k = 0; k < 3; ++k) {
                pvI[k] = 0.f; pvR[k] = 0.f;
                if (soff[k] >= 0) {
                    pvI[k] = ibn[soff[k]];
                    pvR[k] = rbn[soff[k]];
                }
            }
        }

        // ---- unpack a1 offsets (conv1-local regs) ----
        int a1o[4];
        #pragma unroll
        for (int j = 0; j < 4; ++j)
            a1o[j] = (int)((a1opk >> (8 * j)) & 0xFFu);

        // ---- conv1 GEMM + fused leaky+pack write to hs ----
        int pr = pr0, pc = pc0;
        if (interior) {
            unsigned short* hp0 = hs + (wv * 16 + kg * 4) * PXS + 2 * n;
            #pragma unroll
            for (int m = 0; m < 7; ++m) {
                int mt = m * 4 + wv;
                if (mt < 25) {   // wave-uniform guard
                    const unsigned int* base = pxc + (pr * XS_W + pc);
                    const unsigned int* a0p  = base + kg * XS_W;   // row kg
                    unsigned int a0d[4], a1d[4];
                    #pragma unroll
                    for (int j = 0; j < 4; ++j) a0d[j] = a0p[j];
                    #pragma unroll
                    for (int j = 0; j < 4; ++j) a1d[j] = base[a1o[j]];
                    bf16x8 a0 = dw4_to_frag(a0d[0], a0d[1], a0d[2], a0d[3]);
                    bf16x8 a1 = dw4_to_frag(a1d[0], a1d[1], a1d[2], a1d[3]);
                    f32x4 d0 = (f32x4){bb0, bb0, bb0, bb0};
                    f32x4 d1 = (f32x4){bb1, bb1, bb1, bb1};
                    d0 = __builtin_amdgcn_mfma_f32_16x16x32_bf16(a0, bfr[0][0], d0, 0, 0, 0);
                    d0 = __builtin_amdgcn_mfma_f32_16x16x32_bf16(a1, bfr[0][1], d0, 0, 0, 0);
                    d1 = __builtin_amdgcn_mfma_f32_16x16x32_bf16(a0, bfr[1][0], d1, 0, 0, 0);
                    d1 = __builtin_amdgcn_mfma_f32_16x16x32_bf16(a1, bfr[1][1], d1, 0, 0, 0);
                    #pragma unroll
                    for (int r = 0; r < 4; ++r) {
                        float h0 = fmaxf(d0[r], 0.1f * d0[r]);
                        float h1 = fmaxf(d1[r], 0.1f * d1[r]);
                        *(unsigned int*)(hp0 + (m * 64 + r) * PXS) = pack_bf2(h0, h1);
                    }
                }
                pc += 4; pr += 3;
                int w = (pc >= 20) ? 1 : 0;
                pc -= 20 * w; pr += w;
            }
        } else {
            #pragma unroll
            for (int m = 0; m < 7; ++m) {
                int mt = m * 4 + wv;
                if (mt < 25) {
                    const unsigned int* base = pxc + (pr * XS_W + pc);
                    const unsigned int* a0p  = base + kg * XS_W;   // row kg
                    unsigned int a0d[4], a1d[4];
                    #pragma unroll
                    for (int j = 0; j < 4; ++j) a0d[j] = a0p[j];
                    #pragma unroll
                    for (int j = 0; j < 4; ++j) a1d[j] = base[a1o[j]];
                    bf16x8 a0 = dw4_to_frag(a0d[0], a0d[1], a0d[2], a0d[3]);
                    bf16x8 a1 = dw4_to_frag(a1d[0], a1d[1], a1d[2], a1d[3]);
                    f32x4 d0 = (f32x4){bb0, bb0, bb0, bb0};
                    f32x4 d1 = (f32x4){bb1, bb1, bb1, bb1};
                    d0 = __builtin_amdgcn_mfma_f32_16x16x32_bf16(a0, bfr[0][0], d0, 0, 0, 0);
                    d0 = __builtin_amdgcn_mfma_f32_16x16x32_bf16(a1, bfr[0][1], d0, 0, 0, 0);
                    d1 = __builtin_amdgcn_mfma_f32_16x16x32_bf16(a0, bfr[1][0], d1, 0, 0, 0);
                    d1 = __builtin_amdgcn_mfma_f32_16x16x32_bf16(a1, bfr[1][1], d1, 0, 0, 0);
                    #pragma unroll
                    for (int r = 0; r < 4; ++r) {
                        int px = mt * 16 + kg * 4 + r;   // D row = (lane>>4)*4 + reg
                        int prr = px / HS_C, pcc = px - prr * HS_C;
                        int gy = gy0 - 2 + prr, gx = gx0 - 2 + pcc;
                        bool inb = ((unsigned)gy < HH) & ((unsigned)gx < WW);
                        float h0 = fmaxf(d0[r], 0.1f * d0[r]);
                        float h1 = fmaxf(d1[r], 0.1f * d1[r]);
                        if (!inb) { h0 = 0.f; h1 = 0.f; }
                        *(unsigned int*)(hs + px * PXS + 2 * n) = pack_bf2(h0, h1);
                    }
                }
                pc += 4; pr += 3;
                int w = (pc >= 20) ? 1 : 0;
                pc -= 20 * w; pr += w;
            }
        }
        __syncthreads();   // B: hs ready

        // ---- conv2: rolling-row MFMA GEMM (5 single-col passes), b2-init ----
        f32x4 acc[4];
        #pragma unroll
        for (int i = 0; i < 4; ++i)
            acc[i] = (f32x4){b2r[0], b2r[1], b2r[2], b2r[3]};

        conv2_pass<0>(hs, w2t, wv, n, kg, acc);
        conv2_pass<1>(hs, w2t, wv, n, kg, acc);
        conv2_pass<2>(hs, w2t, wv, n, kg, acc);
        conv2_pass<3>(hs, w2t, wv, n, kg, acc);
        conv2_pass<4>(hs, w2t, wv, n, kg, acc);

        // ---- epilogue: out = sum_f filt_f * image[y+fy-1][x+fx-1] ----
        int eo[4];
        #pragma unroll
        for (int r2 = 0; r2 < 4; ++r2)
            eo[r2] = (int)((eopk >> (8 * r2)) & 0xFFu);
        #pragma unroll
        for (int i = 0; i < 4; ++i) {
            int py = wv * 4 + i;
            float partial = 0.f;
            #pragma unroll
            for (int r2 = 0; r2 < 4; ++r2)
                partial += acc[i][r2] * xs0f[py * XS_W + n + eo[r2]];   // f>=9 term exact-zero
            partial += __shfl_down(partial, 16, 64);
            partial += __shfl_down(partial, 32, 64);
            if (lane < 16)
                out[((size_t)bb * HH + gy0 + py) * WW + gx0 + n] = partial;
        }
        __syncthreads();   // C: xs0f/pxc/hs free for next batch
    }
}

extern "C" void kernel_launch(void* const* d_in, const int* in_sizes, int n_in,
                              void* d_out, int out_size, void* d_ws, size_t ws_size,
                              hipStream_t stream) {
    const float* image = (const float*)d_in[0];
    const float* refer = (const float*)d_in[1];
    const float* w1    = (const float*)d_in[2];
    const float* b1    = (const float*)d_in[3];
    const float* w2    = (const float*)d_in[4];
    const float* b2    = (const float*)d_in[5];

    unsigned short* w1c = (unsigned short*)d_ws;                   // 4 KB
    unsigned short* w2t = (unsigned short*)((char*)d_ws + 4096);   // 25.6 KB
    // ws re-poisoned before every launch -> prep must (and does) run every call

    hipLaunchKernelGGL(dynfilt_prep, dim3(32), dim3(256), 0, stream, w1, w2, w1c, w2t);

    dim3 grid(WW / TILE, HH / TILE, 1);   // persistent over batch: 1024 blocks
    hipLaunchKernelGGL(dynfilt_main, grid, dim3(256), 0, stream,
                       image, refer, b1, b2, w1c, w2t, (float*)d_out);
}